// Round 1
// baseline (449.372 us; speedup 1.0000x reference)
//
#include <hip/hip_runtime.h>

typedef unsigned short u16;
typedef __attribute__((ext_vector_type(8))) short short8;
typedef __attribute__((ext_vector_type(4))) float f32x4;

#define AS1 __attribute__((address_space(1)))
#define AS3 __attribute__((address_space(3)))

// Problem constants
constexpr int Bn = 4, Tn = 2048, Cn = 1024, Hn = 16, Dn = 64;
constexpr float SCL = 0.125f; // D^-0.5

__device__ __forceinline__ u16 f2bf(float f) {
  union { float f; unsigned u; } v; v.f = f;
  unsigned r = v.u + 0x7FFFu + ((v.u >> 16) & 1u);
  return (u16)(r >> 16);
}

__global__ void cast_f32_to_bf16(const float* __restrict__ in, u16* __restrict__ out, int n4) {
  int i = blockIdx.x * 256 + threadIdx.x;
  if (i >= n4) return;
  float4 v = ((const float4*)in)[i];
  ushort4 o;
  o.x = f2bf(v.x); o.y = f2bf(v.y); o.z = f2bf(v.z); o.w = f2bf(v.w);
  ((ushort4*)out)[i] = o;
}

__device__ __forceinline__ void store_out(u16* p, float v) { *p = f2bf(v); }
__device__ __forceinline__ void store_out(float* p, float v) { *p = v; }

// C[m,n] = sum_k A[m,k]*B[n,k] + bias[n]   (NT GEMM, bf16 in, f32 acc)
// 128x128 tile, BK=32, 256 threads (4 waves, each 64x64 = 4x4 frags of 16x16)
template <typename OT>
__global__ __launch_bounds__(256) void gemm_nt(
    const u16* __restrict__ A, const u16* __restrict__ Bm,
    const float* __restrict__ bias, OT* __restrict__ C,
    int M, int N, int K)
{
  __shared__ u16 As[128 * 32];
  __shared__ u16 Bs[128 * 32];
  const int tid = threadIdx.x;
  const int lane = tid & 63;
  const int wave = tid >> 6;
  const int m0 = blockIdx.y * 128;
  const int n0 = blockIdx.x * 128;
  const int wr = (wave >> 1) * 64;   // wave row offset in tile
  const int wc = (wave & 1) * 64;    // wave col offset in tile
  const int l15 = lane & 15;
  const int lg = lane >> 4;

  f32x4 acc[4][4] = {};

  for (int kt = 0; kt < K; kt += 32) {
    // ---- stage A,B tiles (128x32 bf16 each) via global_load_lds, 16B/lane ----
    // chunk c (of 8 bf16): row = c>>2, cc = c&3. LDS linear dest; global source
    // pre-swizzled with involution cc ^= (row>>1)&3 (bank-conflict-free reads).
#pragma unroll
    for (int it = 0; it < 2; ++it) {
      int c = it * 256 + tid;
      int row = c >> 2;
      int cc = c & 3;
      int cs = cc ^ ((row >> 1) & 3);
      const u16* ga = A + (m0 + row) * K + kt + cs * 8;
      __builtin_amdgcn_global_load_lds((const AS1 void*)ga, (AS3 void*)(As + c * 8), 16, 0, 0);
      const u16* gb = Bm + (n0 + row) * K + kt + cs * 8;
      __builtin_amdgcn_global_load_lds((const AS1 void*)gb, (AS3 void*)(Bs + c * 8), 16, 0, 0);
    }
    __syncthreads();

    // ---- LDS -> fragments (swizzled read) ----
    short8 af[4], bfr[4];
#pragma unroll
    for (int i = 0; i < 4; ++i) {
      int rowa = wr + i * 16 + l15;
      int csa = lg ^ ((rowa >> 1) & 3);
      af[i] = *(const short8*)(As + (rowa * 32 + csa * 8));
      int rowb = wc + i * 16 + l15;
      int csb = lg ^ ((rowb >> 1) & 3);
      bfr[i] = *(const short8*)(Bs + (rowb * 32 + csb * 8));
    }
#pragma unroll
    for (int i = 0; i < 4; ++i)
#pragma unroll
      for (int j = 0; j < 4; ++j)
        acc[i][j] = __builtin_amdgcn_mfma_f32_16x16x32_bf16(af[i], bfr[j], acc[i][j], 0, 0, 0);
    __syncthreads();
  }

  // ---- epilogue: C/D layout col=lane&15, row=(lane>>4)*4+r ----
#pragma unroll
  for (int i = 0; i < 4; ++i) {
    int rowg = m0 + wr + i * 16 + lg * 4;
#pragma unroll
    for (int j = 0; j < 4; ++j) {
      int colg = n0 + wc + j * 16 + l15;
      float bv = bias[colg];
#pragma unroll
      for (int r = 0; r < 4; ++r)
        store_out(C + (size_t)(rowg + r) * N + colg, acc[i][j][r] + bv);
    }
  }
}

// Causal flash attention. 1 wave per block, 16 q-rows per block, KT=32 key tiles.
// qkv: [B*T][3C] bf16 (q at +0, k at +1024, v at +2048 within row)
// att: [B*T][C] bf16 out ([B,T,H,D] flattened)
__global__ __launch_bounds__(64) void attn_kernel(
    const u16* __restrict__ qkv, u16* __restrict__ att)
{
  __shared__ u16 p_lds[16 * 32];
  const int lane = threadIdx.x;
  const int l15 = lane & 15;
  const int lg = lane >> 4;
  const int bh = blockIdx.x >> 7;      // b*H + h
  const int qt = blockIdx.x & 127;     // q tile (T/16 = 128)
  const int b = bh >> 4;
  const int h = bh & 15;
  const int q0 = qt * 16;
  const int rowbase = b * Tn;
  const int koff = Cn + h * Dn;
  const int voff = 2 * Cn + h * Dn;

  // Q fragments: A-layout lane l: row=l&15, k(d) = dc*32 + (l>>4)*8 + e
  short8 qf0, qf1;
  {
    const u16* qp = qkv + (rowbase + q0 + l15) * (3 * Cn) + h * Dn + lg * 8;
    qf0 = *(const short8*)qp;
    qf1 = *(const short8*)(qp + 32);
  }

  float m_r[4], l_r[4];
  f32x4 oacc[4] = {};
#pragma unroll
  for (int r = 0; r < 4; ++r) { m_r[r] = -1e30f; l_r[r] = 0.f; }

  const int qlast = q0 + 15;
  for (int kt = 0; kt <= qlast; kt += 32) {
    // ---- S = Q K^T for 2 sub-tiles of 16 keys ----
    f32x4 s[2];
#pragma unroll
    for (int t = 0; t < 2; ++t) {
      const u16* kp = qkv + (rowbase + kt + t * 16 + l15) * (3 * Cn) + koff + lg * 8;
      short8 kf0 = *(const short8*)kp;
      short8 kf1 = *(const short8*)(kp + 32);
      f32x4 z = {};
      z = __builtin_amdgcn_mfma_f32_16x16x32_bf16(qf0, kf0, z, 0, 0, 0);
      z = __builtin_amdgcn_mfma_f32_16x16x32_bf16(qf1, kf1, z, 0, 0, 0);
      int kcol = kt + t * 16 + l15;
#pragma unroll
      for (int r = 0; r < 4; ++r) {
        float v = z[r] * SCL;
        int qrow = q0 + lg * 4 + r;
        z[r] = (kcol > qrow) ? -1e30f : v;
      }
      s[t] = z;
    }

    // ---- online softmax (rows live in 16-lane groups) ----
    float alpha[4];
#pragma unroll
    for (int r = 0; r < 4; ++r) {
      float mx = fmaxf(s[0][r], s[1][r]);
      mx = fmaxf(mx, __shfl_xor(mx, 1));
      mx = fmaxf(mx, __shfl_xor(mx, 2));
      mx = fmaxf(mx, __shfl_xor(mx, 4));
      mx = fmaxf(mx, __shfl_xor(mx, 8));
      float mnew = fmaxf(m_r[r], mx);
      alpha[r] = __expf(m_r[r] - mnew);
      float p0 = __expf(s[0][r] - mnew);
      float p1 = __expf(s[1][r] - mnew);
      s[0][r] = p0; s[1][r] = p1;
      float ps = p0 + p1;
      ps += __shfl_xor(ps, 1);
      ps += __shfl_xor(ps, 2);
      ps += __shfl_xor(ps, 4);
      ps += __shfl_xor(ps, 8);
      l_r[r] = l_r[r] * alpha[r] + ps;
      m_r[r] = mnew;
    }
#pragma unroll
    for (int j = 0; j < 4; ++j)
#pragma unroll
      for (int r = 0; r < 4; ++r)
        oacc[j][r] *= alpha[r];

    // ---- P: C-layout -> A-layout via per-wave LDS round trip (bf16) ----
#pragma unroll
    for (int t = 0; t < 2; ++t)
#pragma unroll
      for (int r = 0; r < 4; ++r)
        p_lds[(lg * 4 + r) * 32 + t * 16 + l15] = f2bf(s[t][r]);
    asm volatile("s_waitcnt lgkmcnt(0)" ::: "memory");
    __builtin_amdgcn_sched_barrier(0);
    short8 pf = *(const short8*)(p_lds + l15 * 32 + lg * 8);

    // ---- PV: out[16,64] += P[16,32] * V[32,64] ----
#pragma unroll
    for (int j = 0; j < 4; ++j) {
      short8 vf;
#pragma unroll
      for (int e = 0; e < 8; ++e)
        vf[e] = (short)qkv[(rowbase + kt + lg * 8 + e) * (3 * Cn) + voff + j * 16 + l15];
      oacc[j] = __builtin_amdgcn_mfma_f32_16x16x32_bf16(pf, vf, oacc[j], 0, 0, 0);
    }
  }

  // ---- epilogue ----
#pragma unroll
  for (int j = 0; j < 4; ++j)
#pragma unroll
    for (int r = 0; r < 4; ++r) {
      float v = oacc[j][r] / l_r[r];
      att[(rowbase + q0 + lg * 4 + r) * Cn + h * Dn + j * 16 + l15] = f2bf(v);
    }
}

extern "C" void kernel_launch(void* const* d_in, const int* in_sizes, int n_in,
                              void* d_out, int out_size, void* d_ws, size_t ws_size,
                              hipStream_t stream) {
  const float* x      = (const float*)d_in[0];   // [B,T,C]
  const float* w_qkv  = (const float*)d_in[1];   // [3C,C]
  const float* b_qkv  = (const float*)d_in[2];   // [3C]
  const float* w_proj = (const float*)d_in[3];   // [C,C]
  const float* b_proj = (const float*)d_in[4];   // [C]
  float* out = (float*)d_out;                    // [B,T,C]

  char* ws = (char*)d_ws;
  u16* x_bf     = (u16*)(ws);                         // 8192*1024*2  = 16.78 MB
  u16* wqkv_bf  = (u16*)(ws + 16777216);              // 3072*1024*2  =  6.29 MB
  u16* wproj_bf = (u16*)(ws + 16777216 + 6291456);    // 1024*1024*2  =  2.10 MB
  u16* qkv      = (u16*)(ws + 25165824);              // 8192*3072*2  = 50.33 MB
  u16* att      = (u16*)(ws + 75497472);              // 8192*1024*2  = 16.78 MB
                                                      // total 92.27 MB

  const int M = Bn * Tn;  // 8192

  // casts
  cast_f32_to_bf16<<<(M * Cn / 4 + 255) / 256, 256, 0, stream>>>(x, x_bf, M * Cn / 4);
  cast_f32_to_bf16<<<(3 * Cn * Cn / 4 + 255) / 256, 256, 0, stream>>>(w_qkv, wqkv_bf, 3 * Cn * Cn / 4);
  cast_f32_to_bf16<<<(Cn * Cn / 4 + 255) / 256, 256, 0, stream>>>(w_proj, wproj_bf, Cn * Cn / 4);

  // qkv = x @ w_qkv^T + b_qkv   [8192, 3072] bf16
  gemm_nt<u16><<<dim3(3 * Cn / 128, M / 128), 256, 0, stream>>>(
      x_bf, wqkv_bf, b_qkv, qkv, M, 3 * Cn, Cn);

  // causal flash attention -> att [8192, 1024] bf16
  attn_kernel<<<Bn * Hn * (Tn / 16), 64, 0, stream>>>(qkv, att);

  // out = att @ w_proj^T + b_proj   [8192, 1024] f32
  gemm_nt<float><<<dim3(Cn / 128, M / 128), 256, 0, stream>>>(
      att, wproj_bf, b_proj, out, M, Cn, Cn);
}